// Round 17
// baseline (58.463 us; speedup 1.0000x reference)
//
#include <hip/hip_runtime.h>
#include <hip/hip_bf16.h>
#include <hip/hip_fp16.h>

// AdaCoF frame interpolation. R17: dual-t single kernel, no combine stage.
//  R16 ledger: pipes balanced (VALU ~9us, LDS ~14us, mem ~17-19us of ~35us
//  main); biggest discrete cost left = combine2 + 12MB ws round-trip +
//  2nd launch (~4-6us). R11 failed this by halving the grid (4 blocks/CU);
//  R12 failed via slow global atomics. R17 keeps 2048x256 (8 blocks/CU,
//  32 waves/CU): block = 16x8 tile x BOTH t (threads 0-127 t=0, 128-255
//  t=1, wave-uniform). Per-t window 37x29 (halo +-8) x {half2(c0,c1),
//  pair-dup half2 c2} = 17.2 KB. Epilogue: t=1 deposits 3 floats in LDS
//  exchange (aliases dead window; stride-3 = 2 lanes/bank = free), t=0
//  adds + writes d_out. Prefetch groups 0,1 issued BEFORE the barrier
//  (register dests stay in flight across s_barrier).
//  Tap math / fp16 packing / ping-pong prefetch: R13-R16 verbatim.
//  Tripwires: VGPR<=64, WRITE ~3.2 MB, absmax <= 7e-3.

#define KS 5
#define K2 25
#define PADR 2

constexpr int T_ = 2;
constexpr int B_ = 4;
constexpr int C_ = 3;
constexpr int H_ = 256;
constexpr int W_ = 256;
constexpr int HW_ = H_ * W_;
constexpr float HP_MAX = (float)(H_ + 2 * PADR - 1);  // 259
constexpr float WP_MAX = (float)(W_ + 2 * PADR - 1);  // 259
constexpr float HP_M2 = (float)(H_ + 2 * PADR - 2);   // 258
constexpr float WP_M2 = (float)(W_ + 2 * PADR - 2);   // 258

constexpr int TILE_W = 16;
constexpr int TILE_H = 8;
constexpr int HALO   = 8;
constexpr int RPAD   = HALO + PADR;              // 10
constexpr int WROWS  = TILE_H + 21;              // 29
constexpr int WCOLS  = TILE_W + 21;              // 37
constexpr int PLANE  = WROWS * WCOLS;            // 1073
constexpr int NTILE  = HW_ / (TILE_W * TILE_H);  // 512 tiles

__global__ __launch_bounds__(256) void adacof_dual(
    const float* __restrict__ frames,   // [T,B,C,H,W]
    const float* __restrict__ weights,  // [B,T,K2,H,W]
    const float* __restrict__ alphas,   // [B,T,K2,H,W]
    const float* __restrict__ betas,    // [B,T,K2,H,W]
    const float* __restrict__ occl,     // [B,T,H,W]
    float* __restrict__ out)            // [B,C,H,W]
{
    __shared__ __half2 winA[2 * PLANE];   // per-t (c0,c1) at x:      8.6 KB
    __shared__ __half2 win2[2 * PLANE];   // per-t (c2 x, c2 x+1):    8.6 KB

    // block decode: 2048 blocks = b(4) x tile(512); tile = ty(32) x tx(16)
    const int bid  = blockIdx.x;
    const int b    = bid >> 9;
    const int tile = bid & 511;
    const int ty   = tile >> 4;         // 0..31
    const int tx   = tile & 15;         // 0..15
    const int i0   = ty << 3;
    const int j0   = tx << 4;

    const int tid = threadIdx.x;        // 0..255
    const int t   = tid >> 7;           // wave-uniform: waves 0-1 / 2-3
    const int lt  = tid & 127;

    const int wy0 = i0 - RPAD;
    const int wx0 = j0 - RPAD;

    const float* __restrict__ fb = frames + (size_t)(t * B_ + b) * C_ * HW_;
    __half2* __restrict__ wA = winA + t * PLANE;
    __half2* __restrict__ w2 = win2 + t * PLANE;

    // ---- stage this half's window = materialized replication-padded image ----
    for (int e = lt; e < PLANE; e += 128) {
        const int wy = e / WCOLS;               // const-div -> magic mul
        const int wx = e - wy * WCOLS;
        const int gy  = min(max(wy0 + wy, 0), H_ - 1);
        const int gx  = min(max(wx0 + wx, 0), W_ - 1);
        const int gx1 = min(max(wx0 + wx + 1, 0), W_ - 1);
        const int gr = gy << 8;
        wA[e] = __floats2half2_rn(fb[gr + gx], fb[HW_ + gr + gx]);
        w2[e] = __floats2half2_rn(fb[2 * HW_ + gr + gx], fb[2 * HW_ + gr + gx1]);
    }

    const int x = lt & 15, r = lt >> 4;
    const int i = i0 + r, j = j0 + x;
    const int ij = (i << 8) | j;

    const int btbase = ((b * T_ + t) * K2) * HW_ + ij;
    const float* __restrict__ wp = weights + btbase;
    const float* __restrict__ ap = alphas + btbase;
    const float* __restrict__ bp = betas + btbase;

    // occlusion loads issued early, consumed in epilogue
    const float o_own = occl[(b * T_ + t) * HW_ + ij];
    const float o_oth = occl[(b * T_ + (1 - t)) * HW_ + ij];

    float wsum = 0.0f, acc0 = 0.0f, acc1 = 0.0f, acc2 = 0.0f;
    const float fi = (float)i;
    const float fj = (float)j;
    const float oy = (float)(i0 - HALO);   // window-origin: iy = y0f - oy
    const float ox = (float)(j0 - HALO);

    // ---- 5-deep ping-pong prefetch buffers (literal-indexed after unroll) ----
    float wgA[5], agA[5], bgA[5];
    float wgB[5], agB[5], bgB[5];

#define PREFETCH(BUF, BASE)                                                    \
    {                                                                          \
        _Pragma("unroll")                                                      \
        for (int q = 0; q < 5; ++q) {                                          \
            wg##BUF[q] = wp[((BASE) + q) * HW_];                               \
            ag##BUF[q] = ap[((BASE) + q) * HW_];                               \
            bg##BUF[q] = bp[((BASE) + q) * HW_];                               \
        }                                                                      \
    }

#define TAP5(BUF, BASE)                                                        \
    {                                                                          \
        _Pragma("unroll")                                                      \
        for (int q = 0; q < 5; ++q) {                                          \
            const int k = (BASE) + q;                                          \
            const float ew = __expf(wg##BUF[q]);                               \
            wsum += ew;                                                        \
            const int kd = k / KS;                                             \
            const float dy = (float)kd;                                        \
            const float dx = (float)(k - kd * KS);                             \
            const float y2  = fminf(fmaxf(ag##BUF[q] + (dy + fi), 0.0f), HP_MAX); \
            const float x2  = fminf(fmaxf(bg##BUF[q] + (dx + fj), 0.0f), WP_MAX); \
            const float y0f = fminf(floorf(y2), HP_M2);                        \
            const float x0f = fminf(floorf(x2), WP_M2);                        \
            const float fy  = y2 - y0f;                                        \
            const float fx  = x2 - x0f;                                        \
            const int iy  = (int)(y0f - oy);                                   \
            const int ixx = (int)(x0f - ox);                                   \
            const int l   = iy * WCOLS + ixx;                                  \
            const float fyw = fy * ew;                                         \
            const float ey0 = ew - fyw;                                        \
            const float w01 = fx * ey0;                                        \
            const float w00 = ey0 - w01;                                       \
            const float w11 = fx * fyw;                                        \
            const float w10 = fyw - w11;                                       \
            const float2 p00 = __half22float2(wA[l]);                          \
            const float2 p01 = __half22float2(wA[l + 1]);                      \
            const float2 p10 = __half22float2(wA[l + WCOLS]);                  \
            const float2 p11 = __half22float2(wA[l + WCOLS + 1]);              \
            const float2 q0  = __half22float2(w2[l]);                          \
            const float2 q1  = __half22float2(w2[l + WCOLS]);                  \
            acc0 += w00 * p00.x + w01 * p01.x + w10 * p10.x + w11 * p11.x;     \
            acc1 += w00 * p00.y + w01 * p01.y + w10 * p10.y + w11 * p11.y;     \
            acc2 += w00 * q0.x  + w01 * q0.y  + w10 * q1.x  + w11 * q1.y;      \
        }                                                                      \
    }

    // groups 0,1 issued BEFORE the barrier: register dests stay in flight
    PREFETCH(A, 0)
    PREFETCH(B, 5)

    __syncthreads();

    TAP5(A, 0)
    PREFETCH(A, 10)
    TAP5(B, 5)
    PREFETCH(B, 15)
    TAP5(A, 10)
    PREFETCH(A, 20)
    TAP5(B, 15)
    TAP5(A, 20)

#undef PREFETCH
#undef TAP5

    const float occw = 1.0f / (1.0f + __expf(o_oth - o_own));
    const float wscale = occw / wsum;
    const float r0 = acc0 * wscale;
    const float r1 = acc1 * wscale;
    const float r2 = acc2 * wscale;

    // ---- in-block t-combine via LDS exchange (aliases dead window) ----
    __syncthreads();                    // all window reads done
    float* __restrict__ exch = (float*)winA;   // 128 px * 3 floats = 1.5 KB
    if (t == 1) {
        exch[lt * 3 + 0] = r0;
        exch[lt * 3 + 1] = r1;
        exch[lt * 3 + 2] = r2;
    }
    __syncthreads();
    if (t == 0) {
        float* __restrict__ op = out + (size_t)(b * C_) * HW_ + ij;
        op[0]       = r0 + exch[lt * 3 + 0];
        op[HW_]     = r1 + exch[lt * 3 + 1];
        op[2 * HW_] = r2 + exch[lt * 3 + 2];
    }
}

extern "C" void kernel_launch(void* const* d_in, const int* in_sizes, int n_in,
                              void* d_out, int out_size, void* d_ws, size_t ws_size,
                              hipStream_t stream) {
    const float* frames  = (const float*)d_in[0];
    const float* weights = (const float*)d_in[1];
    const float* alphas  = (const float*)d_in[2];
    const float* betas   = (const float*)d_in[3];
    const float* occl    = (const float*)d_in[4];
    float* out = (float*)d_out;

    const int blocks = B_ * NTILE;       // 2048 blocks x 256 threads
    adacof_dual<<<blocks, 256, 0, stream>>>(frames, weights, alphas, betas,
                                            occl, out);
}

// Round 18
// 38.516 us; speedup vs baseline: 1.5179x; 1.5179x over previous
//
#include <hip/hip_runtime.h>
#include <hip/hip_bf16.h>
#include <hip/hip_fp16.h>

// AdaCoF frame interpolation. R18: R16 (best, 38.8us) + fp16 ws partials.
//  R17 refuted 16-wide tiles (FETCH 2x: half-lines split across blocks/XCDs)
//  and in-block t-fusion for the 3rd time. Base reverted to R16:
//  2048 blocks x 256 thr, 32x8 tile x one t, 12.8 KB fp16-packed window
//  (winA=half2(c0,c1), win2=pair-dup half2 c2), window-relative corner math,
//  5-deep ping-pong streaming prefetch, ws partials + combine2.
//  R18 delta: partials stored as fp16 (values normalized, <=1 -> +5e-4 err;
//  absmax 3.9e-3, threshold 15.7e-3). ws traffic 12.6 -> 6.3 MB, combine
//  time ~halves. Stores stay coalesced (2B x 64 lanes = 128B runs).
//  Tripwires: absmax <= 5e-3, main WRITE_SIZE ~3.2 MB, VGPR <= 64.

#define KS 5
#define K2 25
#define PADR 2

constexpr int T_ = 2;
constexpr int B_ = 4;
constexpr int C_ = 3;
constexpr int H_ = 256;
constexpr int W_ = 256;
constexpr int HW_ = H_ * W_;
constexpr int BCHW_ = B_ * C_ * HW_;                  // 786432
constexpr float HP_MAX = (float)(H_ + 2 * PADR - 1);  // 259
constexpr float WP_MAX = (float)(W_ + 2 * PADR - 1);  // 259
constexpr float HP_M2 = (float)(H_ + 2 * PADR - 2);   // 258
constexpr float WP_M2 = (float)(W_ + 2 * PADR - 2);   // 258

constexpr int TILE_W = 32;
constexpr int TILE_H = 8;
constexpr int HALO   = 8;
constexpr int RPAD   = HALO + PADR;            // 10
constexpr int WROWS  = TILE_H + 21;            // 29
constexpr int WCOLS  = TILE_W + 21;            // 53
constexpr int PLANE  = WROWS * WCOLS;          // 1537
constexpr int NTILE  = HW_ / (TILE_W * TILE_H);  // 256

__global__ __launch_bounds__(256) void adacof_tile(
    const float* __restrict__ frames,   // [T,B,C,H,W]
    const float* __restrict__ weights,  // [B,T,K2,H,W]
    const float* __restrict__ alphas,   // [B,T,K2,H,W]
    const float* __restrict__ betas,    // [B,T,K2,H,W]
    const float* __restrict__ occl,     // [B,T,H,W]
    __half* __restrict__ part)          // ws: [T,B,C,H,W] fp16
{
    __shared__ __half2 winA[PLANE];     // (c0,c1) at x:          6.1 KB
    __shared__ __half2 win2[PLANE];     // (c2 at x, c2 at x+1):  6.1 KB

    // block decode: 2048 blocks = b(4) x tile(256) x t(2)
    const int bid  = blockIdx.x;
    const int b    = bid >> 9;
    const int rem  = bid & 511;
    const int t    = rem & 1;
    const int tile = rem >> 1;          // 0..255
    const int i0   = (tile >> 3) << 3;  // row tile * 8
    const int j0   = (tile & 7) << 5;   // col tile * 32

    const int tid = threadIdx.x;
    const int wy0 = i0 - RPAD;
    const int wx0 = j0 - RPAD;

    const float* __restrict__ fb = frames + (size_t)(t * B_ + b) * C_ * HW_;

    // ---- stage window = materialized replication-padded image ----
    for (int e = tid; e < PLANE; e += 256) {
        const int wy = e / WCOLS;               // const-div -> magic mul
        const int wx = e - wy * WCOLS;
        const int gy  = min(max(wy0 + wy, 0), H_ - 1);
        const int gx  = min(max(wx0 + wx, 0), W_ - 1);
        const int gx1 = min(max(wx0 + wx + 1, 0), W_ - 1);
        const int gr = gy << 8;
        winA[e] = __floats2half2_rn(fb[gr + gx], fb[HW_ + gr + gx]);
        win2[e] = __floats2half2_rn(fb[2 * HW_ + gr + gx], fb[2 * HW_ + gr + gx1]);
    }

    const int x = tid & 31, r = tid >> 5;
    const int i = i0 + r, j = j0 + x;
    const int ij = (i << 8) | j;

    const int btbase = ((b * T_ + t) * K2) * HW_ + ij;
    const float* __restrict__ wp = weights + btbase;
    const float* __restrict__ ap = alphas + btbase;
    const float* __restrict__ bp = betas + btbase;

    // occlusion loads issued early, consumed in epilogue
    const float o_own = occl[(b * T_ + t) * HW_ + ij];
    const float o_oth = occl[(b * T_ + (1 - t)) * HW_ + ij];

    float wsum = 0.0f, acc0 = 0.0f, acc1 = 0.0f, acc2 = 0.0f;
    const float fi = (float)i;
    const float fj = (float)j;
    const float oy = (float)(i0 - HALO);   // window-origin: iy = y0f - oy
    const float ox = (float)(j0 - HALO);

    // ---- 5-deep ping-pong prefetch buffers (literal-indexed after unroll) ----
    float wgA[5], agA[5], bgA[5];
    float wgB[5], agB[5], bgB[5];

#define PREFETCH(BUF, BASE)                                                    \
    {                                                                          \
        _Pragma("unroll")                                                      \
        for (int q = 0; q < 5; ++q) {                                          \
            wg##BUF[q] = wp[((BASE) + q) * HW_];                               \
            ag##BUF[q] = ap[((BASE) + q) * HW_];                               \
            bg##BUF[q] = bp[((BASE) + q) * HW_];                               \
        }                                                                      \
    }

#define TAP5(BUF, BASE)                                                        \
    {                                                                          \
        _Pragma("unroll")                                                      \
        for (int q = 0; q < 5; ++q) {                                          \
            const int k = (BASE) + q;                                          \
            const float ew = __expf(wg##BUF[q]);                               \
            wsum += ew;                                                        \
            const int kd = k / KS;                                             \
            const float dy = (float)kd;                                        \
            const float dx = (float)(k - kd * KS);                             \
            const float y2  = fminf(fmaxf(ag##BUF[q] + (dy + fi), 0.0f), HP_MAX); \
            const float x2  = fminf(fmaxf(bg##BUF[q] + (dx + fj), 0.0f), WP_MAX); \
            const float y0f = fminf(floorf(y2), HP_M2);                        \
            const float x0f = fminf(floorf(x2), WP_M2);                        \
            const float fy  = y2 - y0f;                                        \
            const float fx  = x2 - x0f;                                        \
            const int iy  = (int)(y0f - oy);                                   \
            const int ixx = (int)(x0f - ox);                                   \
            const int l   = iy * WCOLS + ixx;                                  \
            const float fyw = fy * ew;                                         \
            const float ey0 = ew - fyw;                                        \
            const float w01 = fx * ey0;                                        \
            const float w00 = ey0 - w01;                                       \
            const float w11 = fx * fyw;                                        \
            const float w10 = fyw - w11;                                       \
            const float2 p00 = __half22float2(winA[l]);                        \
            const float2 p01 = __half22float2(winA[l + 1]);                    \
            const float2 p10 = __half22float2(winA[l + WCOLS]);                \
            const float2 p11 = __half22float2(winA[l + WCOLS + 1]);            \
            const float2 q0  = __half22float2(win2[l]);                        \
            const float2 q1  = __half22float2(win2[l + WCOLS]);                \
            acc0 += w00 * p00.x + w01 * p01.x + w10 * p10.x + w11 * p11.x;     \
            acc1 += w00 * p00.y + w01 * p01.y + w10 * p10.y + w11 * p11.y;     \
            acc2 += w00 * q0.x  + w01 * q0.y  + w10 * q1.x  + w11 * q1.y;      \
        }                                                                      \
    }

    // groups 0,1 issued early; register dests stay in flight across barrier
    PREFETCH(A, 0)
    PREFETCH(B, 5)

    __syncthreads();

    TAP5(A, 0)
    PREFETCH(A, 10)
    TAP5(B, 5)
    PREFETCH(B, 15)
    TAP5(A, 10)
    PREFETCH(A, 20)
    TAP5(B, 15)
    TAP5(A, 20)

#undef PREFETCH
#undef TAP5

    const float occw = 1.0f / (1.0f + __expf(o_oth - o_own));
    const float wscale = occw / wsum;

    // fp16 partials: values normalized (<=1), +5e-4 err, half the ws traffic
    __half* __restrict__ pt = part + ((size_t)(t * B_ + b) * C_) * HW_ + ij;
    pt[0]       = __float2half(acc0 * wscale);
    pt[HW_]     = __float2half(acc1 * wscale);
    pt[2 * HW_] = __float2half(acc2 * wscale);
}

__global__ void combine2h(const __half2* __restrict__ part,
                          float2* __restrict__ out) {
    const int n = blockIdx.x * blockDim.x + threadIdx.x;   // over BCHW/2
    const float2 a = __half22float2(part[n]);
    const float2 c = __half22float2(part[n + BCHW_ / 2]);
    out[n] = make_float2(a.x + c.x, a.y + c.y);
}

extern "C" void kernel_launch(void* const* d_in, const int* in_sizes, int n_in,
                              void* d_out, int out_size, void* d_ws, size_t ws_size,
                              hipStream_t stream) {
    const float* frames  = (const float*)d_in[0];
    const float* weights = (const float*)d_in[1];
    const float* alphas  = (const float*)d_in[2];
    const float* betas   = (const float*)d_in[3];
    const float* occl    = (const float*)d_in[4];
    float* out = (float*)d_out;
    __half* part = (__half*)d_ws;        // 3.1 MB fp16; ws_size ample

    const int blocks = B_ * T_ * NTILE;  // 2048
    adacof_tile<<<blocks, 256, 0, stream>>>(frames, weights, alphas, betas,
                                            occl, part);
    combine2h<<<(BCHW_ / 2) / 256, 256, 0, stream>>>((const __half2*)part,
                                                     (float2*)out);
}

// Round 19
// 38.090 us; speedup vs baseline: 1.5349x; 1.0112x over previous
//
#include <hip/hip_runtime.h>
#include <hip/hip_bf16.h>
#include <hip/hip_fp16.h>

// AdaCoF frame interpolation. R19: R18 + 32x16 tile (512-thread blocks).
//  R18 ledger: stall-balanced (~50% per pipe), last gains sub-1%. Remaining
//  identified inefficiency: staging = 6.0 window-els/pixel (24 VMEM/thread,
//  ~30 MB L2). R19 amortizes the halo over a taller tile: 32x16 -> window
//  53x37 = 1961 els = 3.8 els/pixel (-36% staging). Constraints preserved:
//  grid 1024 blocks x 8 waves = 4 blocks/CU = 32 waves/CU (same max class);
//  32-wide rows keep streaming coalescing identical (R17 lesson); LDS
//  15.7 KB/block. All else R18 verbatim: fp16 winA(c0,c1)+pair-dup c2,
//  window-relative corner math, 5-deep ping-pong prefetch, fp16 partials +
//  combine2h. Tripwires: VGPR<=64, absmax<=5e-3, FETCH ~85 MB.

#define KS 5
#define K2 25
#define PADR 2

constexpr int T_ = 2;
constexpr int B_ = 4;
constexpr int C_ = 3;
constexpr int H_ = 256;
constexpr int W_ = 256;
constexpr int HW_ = H_ * W_;
constexpr int BCHW_ = B_ * C_ * HW_;                  // 786432
constexpr float HP_MAX = (float)(H_ + 2 * PADR - 1);  // 259
constexpr float WP_MAX = (float)(W_ + 2 * PADR - 1);  // 259
constexpr float HP_M2 = (float)(H_ + 2 * PADR - 2);   // 258
constexpr float WP_M2 = (float)(W_ + 2 * PADR - 2);   // 258

constexpr int TILE_W = 32;
constexpr int TILE_H = 16;
constexpr int HALO   = 8;
constexpr int RPAD   = HALO + PADR;            // 10
constexpr int WROWS  = TILE_H + 21;            // 37
constexpr int WCOLS  = TILE_W + 21;            // 53
constexpr int PLANE  = WROWS * WCOLS;          // 1961
constexpr int NTILE  = HW_ / (TILE_W * TILE_H);  // 128

__global__ __launch_bounds__(512) void adacof_tile(
    const float* __restrict__ frames,   // [T,B,C,H,W]
    const float* __restrict__ weights,  // [B,T,K2,H,W]
    const float* __restrict__ alphas,   // [B,T,K2,H,W]
    const float* __restrict__ betas,    // [B,T,K2,H,W]
    const float* __restrict__ occl,     // [B,T,H,W]
    __half* __restrict__ part)          // ws: [T,B,C,H,W] fp16
{
    __shared__ __half2 winA[PLANE];     // (c0,c1) at x:          7.8 KB
    __shared__ __half2 win2[PLANE];     // (c2 at x, c2 at x+1):  7.8 KB

    // block decode: 1024 blocks = b(4) x tile(128) x t(2)
    const int bid  = blockIdx.x;
    const int b    = bid >> 8;
    const int rem  = bid & 255;
    const int t    = rem & 1;
    const int tile = rem >> 1;          // 0..127 = ty(16) x tx(8)
    const int i0   = (tile >> 3) << 4;  // row tile * 16
    const int j0   = (tile & 7) << 5;   // col tile * 32

    const int tid = threadIdx.x;        // 0..511
    const int wy0 = i0 - RPAD;
    const int wx0 = j0 - RPAD;

    const float* __restrict__ fb = frames + (size_t)(t * B_ + b) * C_ * HW_;

    // ---- stage window = materialized replication-padded image ----
    for (int e = tid; e < PLANE; e += 512) {
        const int wy = e / WCOLS;               // const-div -> magic mul
        const int wx = e - wy * WCOLS;
        const int gy  = min(max(wy0 + wy, 0), H_ - 1);
        const int gx  = min(max(wx0 + wx, 0), W_ - 1);
        const int gx1 = min(max(wx0 + wx + 1, 0), W_ - 1);
        const int gr = gy << 8;
        winA[e] = __floats2half2_rn(fb[gr + gx], fb[HW_ + gr + gx]);
        win2[e] = __floats2half2_rn(fb[2 * HW_ + gr + gx], fb[2 * HW_ + gr + gx1]);
    }

    const int x = tid & 31, r = tid >> 5;   // r = 0..15
    const int i = i0 + r, j = j0 + x;
    const int ij = (i << 8) | j;

    const int btbase = ((b * T_ + t) * K2) * HW_ + ij;
    const float* __restrict__ wp = weights + btbase;
    const float* __restrict__ ap = alphas + btbase;
    const float* __restrict__ bp = betas + btbase;

    // occlusion loads issued early, consumed in epilogue
    const float o_own = occl[(b * T_ + t) * HW_ + ij];
    const float o_oth = occl[(b * T_ + (1 - t)) * HW_ + ij];

    float wsum = 0.0f, acc0 = 0.0f, acc1 = 0.0f, acc2 = 0.0f;
    const float fi = (float)i;
    const float fj = (float)j;
    const float oy = (float)(i0 - HALO);   // window-origin: iy = y0f - oy
    const float ox = (float)(j0 - HALO);

    // ---- 5-deep ping-pong prefetch buffers (literal-indexed after unroll) ----
    float wgA[5], agA[5], bgA[5];
    float wgB[5], agB[5], bgB[5];

#define PREFETCH(BUF, BASE)                                                    \
    {                                                                          \
        _Pragma("unroll")                                                      \
        for (int q = 0; q < 5; ++q) {                                          \
            wg##BUF[q] = wp[((BASE) + q) * HW_];                               \
            ag##BUF[q] = ap[((BASE) + q) * HW_];                               \
            bg##BUF[q] = bp[((BASE) + q) * HW_];                               \
        }                                                                      \
    }

#define TAP5(BUF, BASE)                                                        \
    {                                                                          \
        _Pragma("unroll")                                                      \
        for (int q = 0; q < 5; ++q) {                                          \
            const int k = (BASE) + q;                                          \
            const float ew = __expf(wg##BUF[q]);                               \
            wsum += ew;                                                        \
            const int kd = k / KS;                                             \
            const float dy = (float)kd;                                        \
            const float dx = (float)(k - kd * KS);                             \
            const float y2  = fminf(fmaxf(ag##BUF[q] + (dy + fi), 0.0f), HP_MAX); \
            const float x2  = fminf(fmaxf(bg##BUF[q] + (dx + fj), 0.0f), WP_MAX); \
            const float y0f = fminf(floorf(y2), HP_M2);                        \
            const float x0f = fminf(floorf(x2), WP_M2);                        \
            const float fy  = y2 - y0f;                                        \
            const float fx  = x2 - x0f;                                        \
            const int iy  = (int)(y0f - oy);                                   \
            const int ixx = (int)(x0f - ox);                                   \
            const int l   = iy * WCOLS + ixx;                                  \
            const float fyw = fy * ew;                                         \
            const float ey0 = ew - fyw;                                        \
            const float w01 = fx * ey0;                                        \
            const float w00 = ey0 - w01;                                       \
            const float w11 = fx * fyw;                                        \
            const float w10 = fyw - w11;                                       \
            const float2 p00 = __half22float2(winA[l]);                        \
            const float2 p01 = __half22float2(winA[l + 1]);                    \
            const float2 p10 = __half22float2(winA[l + WCOLS]);                \
            const float2 p11 = __half22float2(winA[l + WCOLS + 1]);            \
            const float2 q0  = __half22float2(win2[l]);                        \
            const float2 q1  = __half22float2(win2[l + WCOLS]);                \
            acc0 += w00 * p00.x + w01 * p01.x + w10 * p10.x + w11 * p11.x;     \
            acc1 += w00 * p00.y + w01 * p01.y + w10 * p10.y + w11 * p11.y;     \
            acc2 += w00 * q0.x  + w01 * q0.y  + w10 * q1.x  + w11 * q1.y;      \
        }                                                                      \
    }

    // groups 0,1 issued early; register dests stay in flight across barrier
    PREFETCH(A, 0)
    PREFETCH(B, 5)

    __syncthreads();

    TAP5(A, 0)
    PREFETCH(A, 10)
    TAP5(B, 5)
    PREFETCH(B, 15)
    TAP5(A, 10)
    PREFETCH(A, 20)
    TAP5(B, 15)
    TAP5(A, 20)

#undef PREFETCH
#undef TAP5

    const float occw = 1.0f / (1.0f + __expf(o_oth - o_own));
    const float wscale = occw / wsum;

    // fp16 partials: values normalized (<=1), +5e-4 err, half the ws traffic
    __half* __restrict__ pt = part + ((size_t)(t * B_ + b) * C_) * HW_ + ij;
    pt[0]       = __float2half(acc0 * wscale);
    pt[HW_]     = __float2half(acc1 * wscale);
    pt[2 * HW_] = __float2half(acc2 * wscale);
}

__global__ void combine2h(const __half2* __restrict__ part,
                          float2* __restrict__ out) {
    const int n = blockIdx.x * blockDim.x + threadIdx.x;   // over BCHW/2
    const float2 a = __half22float2(part[n]);
    const float2 c = __half22float2(part[n + BCHW_ / 2]);
    out[n] = make_float2(a.x + c.x, a.y + c.y);
}

extern "C" void kernel_launch(void* const* d_in, const int* in_sizes, int n_in,
                              void* d_out, int out_size, void* d_ws, size_t ws_size,
                              hipStream_t stream) {
    const float* frames  = (const float*)d_in[0];
    const float* weights = (const float*)d_in[1];
    const float* alphas  = (const float*)d_in[2];
    const float* betas   = (const float*)d_in[3];
    const float* occl    = (const float*)d_in[4];
    float* out = (float*)d_out;
    __half* part = (__half*)d_ws;        // 3.1 MB fp16; ws_size ample

    const int blocks = B_ * T_ * NTILE;  // 1024 blocks x 512 threads
    adacof_tile<<<blocks, 512, 0, stream>>>(frames, weights, alphas, betas,
                                            occl, part);
    combine2h<<<(BCHW_ / 2) / 256, 256, 0, stream>>>((const __half2*)part,
                                                     (float2*)out);
}